// Round 4
// baseline (19703.392 us; speedup 1.0000x reference)
//
#include <hip/hip_runtime.h>
#include <hip/hip_bf16.h>
#include <math.h>

#define B_  32
#define T_  512
#define D_  1024
#define H_  1024
#define G4_ 4096
#define NB  256
#define NT  512

typedef __attribute__((ext_vector_type(8))) short short8;
typedef __attribute__((ext_vector_type(4))) float f32x4;

__device__ __forceinline__ float hardsig(float z) {
    return fminf(fmaxf(0.2f * z + 0.5f, 0.0f), 1.0f);
}
__device__ __forceinline__ float fast_tanh(float x) {
    float ax = fabsf(x);
    float e  = __expf(-2.0f * ax);          // v_exp_f32-based
    float t  = (1.0f - e) / (1.0f + e);
    return copysignf(t, x);
}
// split fp32 into hi+lo bf16 (RTN)
__device__ __forceinline__ void split2(float f, short& hi, short& lo) {
    __hip_bfloat16 h = __float2bfloat16(f);
    float hf = __bfloat162float(h);
    __hip_bfloat16 l = __float2bfloat16(f - hf);
    hi = *(short*)&h; lo = *(short*)&l;
}
// 16B coherent (L2-bypassing) load of 8 bf16
__device__ __forceinline__ short8 ld16_coh(const unsigned short* p) {
    const unsigned long long* q = (const unsigned long long*)p;
    unsigned long long a = __hip_atomic_load(q + 0, __ATOMIC_RELAXED, __HIP_MEMORY_SCOPE_AGENT);
    unsigned long long b = __hip_atomic_load(q + 1, __ATOMIC_RELAXED, __HIP_MEMORY_SCOPE_AGENT);
    union { unsigned long long u[2]; short8 s; } cv;
    cv.u[0] = a; cv.u[1] = b;
    return cv.s;
}
// wait until all 512 producer flags reach >= q (lane-parallel poll)
__device__ __forceinline__ void wait_step(const unsigned* flags, int lane, unsigned q) {
    if (q == 0) return;
    const int base = lane * 8;
    while (true) {
        unsigned m = 0xffffffffu;
        #pragma unroll
        for (int i = 0; i < 8; ++i) {
            unsigned f = __hip_atomic_load(&flags[base + i], __ATOMIC_RELAXED, __HIP_MEMORY_SCOPE_AGENT);
            m = (f < m) ? f : m;
        }
        if (__all((int)(m >= q))) break;
        __builtin_amdgcn_s_sleep(1);
    }
    asm volatile("" ::: "memory");   // no data-load hoisting above the poll
}

__global__ __launch_bounds__(NT, 1)
void lstm_mfma3(const float* __restrict__ x,
                const float* __restrict__ W0, const float* __restrict__ U0, const float* __restrict__ b0,
                const float* __restrict__ W1, const float* __restrict__ U1, const float* __restrict__ b1,
                unsigned short* __restrict__ h1hi, unsigned short* __restrict__ h1lo,  // [T][B][H] bf16
                unsigned short* __restrict__ h2hi, unsigned short* __restrict__ h2lo,  // [2][B][H] bf16
                const unsigned short* __restrict__ zp,   // [B][H] zeros
                unsigned* __restrict__ flags,            // [2*NB] per-wave step flags
                float* __restrict__ out)                 // [B][H]
{
    __shared__ short Wh[2][16384];        // 64 KB  hi-bf16 weights (frag order)
    __shared__ short Wl[2][16384];        // 64 KB  lo-bf16 weights
    __shared__ float red[2][2][4][16][17];// 17 KB  partial C tiles [par][mt][s][row][col+pad]

    const int tid  = threadIdx.x;
    const int bid  = blockIdx.x;
    const int j0   = bid * 4;            // owned h-columns
    const int w    = tid >> 6;
    const int lane = tid & 63;
    const int s    = w >> 1;             // 0,1: x@W waves; 2,3: h@U waves
    const int mt   = w & 1;              // batch half
    const int ln15 = lane & 15;
    const int lhi  = lane >> 4;
    const int b    = mt * 16 + ln15;     // A-row (batch) this lane loads

    const int cb = tid >> 2;             // combine: batch row (tid<128)
    const int cj = tid & 3;              // combine: owned-col idx

    float creg = 0.f;
    float bias[4] = {0.f, 0.f, 0.f, 0.f};

    #pragma unroll
    for (int layer = 0; layer < 2; ++layer) {
        const float* Wmat = layer ? W1 : W0;
        const float* Umat = layer ? U1 : U0;
        const float* bl   = layer ? b1 : b0;

        __syncthreads();  // all waves done with previous layer's LDS
        // ---- convert W,U 16-col slices to split-bf16 fragment layout ----
        for (int m = 0; m < 2; ++m) {
            const float* src = m ? Umat : Wmat;
            for (int fi = tid; fi < 4096; fi += NT) {
                int g = fi & 3, k = fi >> 2;
                float4 v = *(const float4*)&src[(size_t)k * G4_ + (size_t)g * H_ + j0];
                int ki = k >> 5, kf = k & 31;
                int e = kf & 7;
                int flbase = ((kf >> 3) << 4) | (g << 2);
                short hi, lo;
                split2(v.x, hi, lo); Wh[m][ki*512+(flbase+0)*8+e]=hi; Wl[m][ki*512+(flbase+0)*8+e]=lo;
                split2(v.y, hi, lo); Wh[m][ki*512+(flbase+1)*8+e]=hi; Wl[m][ki*512+(flbase+1)*8+e]=lo;
                split2(v.z, hi, lo); Wh[m][ki*512+(flbase+2)*8+e]=hi; Wl[m][ki*512+(flbase+2)*8+e]=lo;
                split2(v.w, hi, lo); Wh[m][ki*512+(flbase+3)*8+e]=hi; Wl[m][ki*512+(flbase+3)*8+e]=lo;
            }
        }
        if (tid < 128) {
            #pragma unroll
            for (int g = 0; g < 4; ++g) bias[g] = bl[(size_t)g * H_ + j0 + cj];
            creg = 0.f;
        }
        __syncthreads();

        for (int t = 0; t < T_; ++t) {
            const int q   = layer * T_ + t;
            const int par = q & 1;
            f32x4 a0 = {0,0,0,0}, a1 = {0,0,0,0}, a2 = {0,0,0,0};

            if (s < 2) {
                // ---------------- x-phase (never waits) ----------------
                if (layer == 0) {
                    const float* xr = x + ((size_t)b * T_ + t) * D_;
                    #pragma unroll 4
                    for (int ki = 0; ki < 16; ++ki) {
                        const int d = s * 512 + ki * 32 + lhi * 8;
                        float4 v0 = *(const float4*)&xr[d];
                        float4 v1 = *(const float4*)&xr[d + 4];
                        short8 ah, al; short hi, lo;
                        split2(v0.x,hi,lo); ah[0]=hi; al[0]=lo;
                        split2(v0.y,hi,lo); ah[1]=hi; al[1]=lo;
                        split2(v0.z,hi,lo); ah[2]=hi; al[2]=lo;
                        split2(v0.w,hi,lo); ah[3]=hi; al[3]=lo;
                        split2(v1.x,hi,lo); ah[4]=hi; al[4]=lo;
                        split2(v1.y,hi,lo); ah[5]=hi; al[5]=lo;
                        split2(v1.z,hi,lo); ah[6]=hi; al[6]=lo;
                        split2(v1.w,hi,lo); ah[7]=hi; al[7]=lo;
                        const int kiG = s * 16 + ki;
                        short8 wh = *(const short8*)&Wh[0][kiG*512 + lane*8];
                        short8 wl = *(const short8*)&Wl[0][kiG*512 + lane*8];
                        a0 = __builtin_amdgcn_mfma_f32_16x16x32_bf16(ah, wh, a0, 0, 0, 0);
                        a1 = __builtin_amdgcn_mfma_f32_16x16x32_bf16(al, wh, a1, 0, 0, 0);
                        a2 = __builtin_amdgcn_mfma_f32_16x16x32_bf16(ah, wl, a2, 0, 0, 0);
                    }
                } else {
                    const unsigned short* xh = h1hi + ((size_t)t * B_ + b) * H_;
                    const unsigned short* xl = h1lo + ((size_t)t * B_ + b) * H_;
                    #pragma unroll 4
                    for (int ki = 0; ki < 16; ++ki) {
                        const int d = s * 512 + ki * 32 + lhi * 8;
                        short8 ah = *(const short8*)&xh[d];
                        short8 al = *(const short8*)&xl[d];
                        const int kiG = s * 16 + ki;
                        short8 wh = *(const short8*)&Wh[0][kiG*512 + lane*8];
                        short8 wl = *(const short8*)&Wl[0][kiG*512 + lane*8];
                        a0 = __builtin_amdgcn_mfma_f32_16x16x32_bf16(ah, wh, a0, 0, 0, 0);
                        a1 = __builtin_amdgcn_mfma_f32_16x16x32_bf16(al, wh, a1, 0, 0, 0);
                        a2 = __builtin_amdgcn_mfma_f32_16x16x32_bf16(ah, wl, a2, 0, 0, 0);
                    }
                }
            } else {
                // ---------------- h-phase: wait for step q-1 globally done ----------------
                wait_step(flags, lane, (unsigned)q);
                const int sk = (s - 2) * 512;
                if (layer == 0) {
                    // unique addresses per t -> plain cached loads safe (first touch after publish)
                    const unsigned short* hh = (t == 0) ? (zp + (size_t)b * H_)
                                                        : (h1hi + ((size_t)(t-1) * B_ + b) * H_);
                    const unsigned short* hl = (t == 0) ? (zp + (size_t)b * H_)
                                                        : (h1lo + ((size_t)(t-1) * B_ + b) * H_);
                    #pragma unroll 4
                    for (int ki = 0; ki < 16; ++ki) {
                        const int d = sk + ki * 32 + lhi * 8;
                        short8 ah = *(const short8*)&hh[d];
                        short8 al = *(const short8*)&hl[d];
                        const int kiG = (s - 2) * 16 + ki;
                        short8 uh = *(const short8*)&Wh[1][kiG*512 + lane*8];
                        short8 ul = *(const short8*)&Wl[1][kiG*512 + lane*8];
                        a0 = __builtin_amdgcn_mfma_f32_16x16x32_bf16(ah, uh, a0, 0, 0, 0);
                        a1 = __builtin_amdgcn_mfma_f32_16x16x32_bf16(al, uh, a1, 0, 0, 0);
                        a2 = __builtin_amdgcn_mfma_f32_16x16x32_bf16(ah, ul, a2, 0, 0, 0);
                    }
                } else {
                    // h2 double-buffer reuses addresses -> bypass caches
                    const unsigned short* hh = (t == 0) ? (zp + (size_t)b * H_)
                                                        : (h2hi + (size_t)((t-1)&1) * B_ * H_ + (size_t)b * H_);
                    const unsigned short* hl = (t == 0) ? (zp + (size_t)b * H_)
                                                        : (h2lo + (size_t)((t-1)&1) * B_ * H_ + (size_t)b * H_);
                    #pragma unroll 4
                    for (int ki = 0; ki < 16; ++ki) {
                        const int d = sk + ki * 32 + lhi * 8;
                        short8 ah = ld16_coh(&hh[d]);
                        short8 al = ld16_coh(&hl[d]);
                        const int kiG = (s - 2) * 16 + ki;
                        short8 uh = *(const short8*)&Wh[1][kiG*512 + lane*8];
                        short8 ul = *(const short8*)&Wl[1][kiG*512 + lane*8];
                        a0 = __builtin_amdgcn_mfma_f32_16x16x32_bf16(ah, uh, a0, 0, 0, 0);
                        a1 = __builtin_amdgcn_mfma_f32_16x16x32_bf16(al, uh, a1, 0, 0, 0);
                        a2 = __builtin_amdgcn_mfma_f32_16x16x32_bf16(ah, ul, a2, 0, 0, 0);
                    }
                }
            }

            f32x4 acc = a0 + a1 + a2;
            #pragma unroll
            for (int i = 0; i < 4; ++i)
                red[par][mt][s][lhi*4+i][ln15] = acc[i];
            __syncthreads();   // the only per-step intra-block barrier

            // ---- combine + state update + coherent publish + flag (waves 0,1) ----
            if (tid < 128) {
                const int rmt = cb >> 4, rr = cb & 15;
                float z[4];
                #pragma unroll
                for (int g = 0; g < 4; ++g) {
                    const int n = g * 4 + cj;
                    z[g] = red[par][rmt][0][rr][n] + red[par][rmt][1][rr][n]
                         + red[par][rmt][2][rr][n] + red[par][rmt][3][rr][n] + bias[g];
                }
                float ig = hardsig(z[0]);
                float fg = hardsig(z[1]);
                float gg = fast_tanh(z[2]);
                float og = hardsig(z[3]);
                creg = fg * creg + ig * gg;
                float hval = og * fast_tanh(creg);
                short hi, lo; split2(hval, hi, lo);
                unsigned uhi = (unsigned short)hi, ulo = (unsigned short)lo;
                unsigned ohi = (unsigned)__shfl_xor((int)uhi, 1);
                unsigned olo = (unsigned)__shfl_xor((int)ulo, 1);
                // even cj of each pair stores the hi-dword (cols e,e+1); odd stores the lo-dword
                const size_t base = (size_t)cb * H_ + j0 + (cj & 2);
                unsigned val = (cj & 1) ? ((ulo << 16) | olo) : ((ohi << 16) | uhi);
                unsigned short* arr;
                size_t off;
                if (layer == 0) { arr = (cj & 1) ? h1lo : h1hi; off = (size_t)t * B_ * H_ + base; }
                else            { arr = (cj & 1) ? h2lo : h2hi; off = (size_t)(t & 1) * B_ * H_ + base; }
                __hip_atomic_store((unsigned*)&arr[off], val,
                                   __ATOMIC_RELAXED, __HIP_MEMORY_SCOPE_AGENT);
                if (layer == 1 && t == T_ - 1) out[(size_t)cb * H_ + j0 + cj] = hval;
                // all 64 lanes' publishes ACKed at LLC before raising the flag
                asm volatile("s_waitcnt vmcnt(0)" ::: "memory");
                if (lane == 0)
                    __hip_atomic_store(&flags[w * NB + bid], (unsigned)(q + 1),
                                       __ATOMIC_RELAXED, __HIP_MEMORY_SCOPE_AGENT);
            }
        }
    }
}

extern "C" void kernel_launch(void* const* d_in, const int* in_sizes, int n_in,
                              void* d_out, int out_size, void* d_ws, size_t ws_size,
                              hipStream_t stream) {
    const float* x  = (const float*)d_in[0];
    const float* W0 = (const float*)d_in[1];
    const float* U0 = (const float*)d_in[2];
    const float* b0 = (const float*)d_in[3];
    const float* W1 = (const float*)d_in[4];
    const float* U1 = (const float*)d_in[5];
    const float* b1 = (const float*)d_in[6];
    float* out = (float*)d_out;

    char* ws = (char*)d_ws;
    const size_t off_h1hi = 0;          // 32 MiB
    const size_t off_h1lo = 33554432;   // 32 MiB
    const size_t off_h2hi = 67108864;   // 128 KiB
    const size_t off_h2lo = 67239936;   // 128 KiB
    const size_t off_zp   = 67371008;   // 128 KiB zeros
    const size_t off_fl   = 67502080;   //   4 KiB flags

    unsigned short* h1hi = (unsigned short*)(ws + off_h1hi);
    unsigned short* h1lo = (unsigned short*)(ws + off_h1lo);
    unsigned short* h2hi = (unsigned short*)(ws + off_h2hi);
    unsigned short* h2lo = (unsigned short*)(ws + off_h2lo);
    unsigned short* zp   = (unsigned short*)(ws + off_zp);
    unsigned* flags      = (unsigned*)(ws + off_fl);

    // reset zero page + flags every launch (graph-capture safe)
    hipMemsetAsync(ws + off_zp, 0, 131072 + 4096, stream);

    hipLaunchKernelGGL(lstm_mfma3, dim3(NB), dim3(NT), 0, stream,
                       x, W0, U0, b0, W1, U1, b1,
                       h1hi, h1lo, h2hi, h2lo, zp, flags, out);
}